// Round 5
// baseline (395.387 us; speedup 1.0000x reference)
//
#include <hip/hip_runtime.h>

#define K_TAGS 128
#define T_MAX  512
#define N_SEQ  512
#define START_TAG 126
#define END_TAG   127
#define LOG2E 1.44269504088896340736f
#define LN2   0.69314718055994530942f

typedef float v2f __attribute__((ext_vector_type(2)));

__device__ __forceinline__ float fexp2(float x) {
#if __has_builtin(__builtin_amdgcn_exp2f)
  return __builtin_amdgcn_exp2f(x);
#else
  return exp2f(x);
#endif
}
__device__ __forceinline__ float flog2(float x) {
#if __has_builtin(__builtin_amdgcn_logf)
  return __builtin_amdgcn_logf(x);
#else
  return __log2f(x);
#endif
}

// DPP quad_perm butterfly stages: 0xB1 = xor1, 0x4E = xor2.
template <int CTRL>
__device__ __forceinline__ float dpp_mov(float x) {
  return __int_as_float(__builtin_amdgcn_update_dpp(
      0, __float_as_int(x), CTRL, 0xF, 0xF, true));
}
// ds_swizzle BitMode: offset = (xor<<10)|(or<<5)|and. xor4 = 0x101F,
// xor8 = 0x201F (within 32-lane halves; partners stay in-group).
template <int OFF>
__device__ __forceinline__ float swz(float x) {
  return __int_as_float(__builtin_amdgcn_ds_swizzle(__float_as_int(x), OFF));
}

// LDS-only barrier: drains lgkmcnt, NOT vmcnt, so the depth-4 global
// feats prefetch stays in flight across steps.
__device__ __forceinline__ void lds_barrier() {
  asm volatile("s_waitcnt lgkmcnt(0)" ::: "memory");
  __builtin_amdgcn_s_barrier();
  asm volatile("" ::: "memory");
}

// One block per sequence, 256 threads = 4 waves.
// Lane (jg=tid>>3, q=tid&7): cols {jg, jg+32, jg+64, jg+96}, rows
// [16q, 16q+16). LINEAR domain: alpha2_j(t) = log2(p_t[j]) + Cc.
// Per step: 4x ds_read_b128 (chunk order c^(q>>1): conflict-free),
// 32 pk_fma (4-deep chains), butterfly xor1/xor2 (DPP) + xor4 (swizzle),
// p' = acc * 2^(f*log2e - D). Rescale: even steps publish 16-lane-row max
// (xor8 swizzle, 1 store) to red16[slot], consume the 2-step-stale slot
// (D = log2(blockmax), hidden under FMA block). One lgkm-only barrier/step.
__global__ __launch_bounds__(256, 2) void crf_fwd_kernel(
    const float* __restrict__ feats,    // [B, T, K]
    const float* __restrict__ trans,    // [K, K]
    const int*   __restrict__ lengths,  // [B]
    float*       __restrict__ partial)  // [B]
{
  const int blk = blockIdx.x;
  // LPT pairing: blocks c and c+256 co-reside on a CU under round-robin
  // dispatch; pair longest with shortest (lengths sorted descending).
  const int b   = (blk < N_SEQ / 2) ? blk : (3 * N_SEQ / 2 - 1 - blk);
  const int tid = (int)threadIdx.x;
  const int jg  = tid >> 3;          // 0..31 (col group)
  const int q   = tid & 7;           // row slice
  const int r0  = q * 16;            // first row of my slice
  const int cs  = q >> 1;            // chunk swizzle (bank spread)

  const int len = lengths[b];
  const float* fb = feats + (size_t)b * (T_MAX * K_TAGS);

  __shared__ __align__(16) float p_sh[2][K_TAGS];
  __shared__ __align__(16) float red16[2][16];
  __shared__ float red8[8];

  // E2 = 2^(trans*log2e), 4 cols x 16 rows per lane, rows stored in
  // swizzled chunk order. All indices compile-time constant.
  v2f E[4][8];
#pragma unroll
  for (int c = 0; c < 4; ++c) {
    const int r = r0 + 4 * (c ^ cs);
#pragma unroll
    for (int k = 0; k < 4; ++k) {
      const int col = jg + 32 * k;
      E[k][2 * c + 0] = v2f{fexp2(trans[(r + 0) * K_TAGS + col] * LOG2E),
                            fexp2(trans[(r + 1) * K_TAGS + col] * LOG2E)};
      E[k][2 * c + 1] = v2f{fexp2(trans[(r + 2) * K_TAGS + col] * LOG2E),
                            fexp2(trans[(r + 3) * K_TAGS + col] * LOG2E)};
    }
  }

  // p(0) = onehot(START); rescale slots init to 1 (D = log2(1) = 0).
  if (q == 0) {
#pragma unroll
    for (int k = 0; k < 4; ++k)
      p_sh[0][jg + 32 * k] = (jg + 32 * k == START_TAG) ? 1.0f : 0.0f;
  }
  if (tid < 32) red16[tid >> 4][tid & 15] = 1.0f;

  float Cc = 0.0f;                       // cumulative log2 normalizer
  float pc0 = 0.f, pc1 = 0.f, pc2 = 0.f, pc3 = 0.f;  // last p (persist)

  // depth-4 prefetch: four named float4 sets, static .x..w access only.
  float4 FA, FB, FC, FD;
  {
    const int tB = (len > 1) ? 1 : 0;
    const int tC = (len > 2) ? 2 : (len - 1);
    const int tD = (len > 3) ? 3 : (len - 1);
    const float* a = fb + jg;
    FA = float4{a[0], a[32], a[64], a[96]};
    a = fb + tB * K_TAGS + jg;
    FB = float4{a[0], a[32], a[64], a[96]};
    a = fb + tC * K_TAGS + jg;
    FC = float4{a[0], a[32], a[64], a[96]};
    a = fb + tD * K_TAGS + jg;
    FD = float4{a[0], a[32], a[64], a[96]};
  }

#define BODY(BUF, F, EVEN, SLOT, TT)                                         \
  {                                                                          \
    const float4 fl = F; /* load issued 4 bodies ago: complete */            \
    const int tp = ((TT) + 4 < len) ? ((TT) + 4) : (len - 1);                \
    const float* fr = fb + tp * K_TAGS + jg;                                 \
    F.x = fr[0]; F.y = fr[32]; F.z = fr[64]; F.w = fr[96];                   \
    lds_barrier();                                                           \
    float D = 0.0f;                                                          \
    if (EVEN) { /* consume 2-step-stale block max */                         \
      const float4 m0 = *reinterpret_cast<const float4*>(&red16[(SLOT)^1][0]);  \
      const float4 m1 = *reinterpret_cast<const float4*>(&red16[(SLOT)^1][4]);  \
      const float4 m2 = *reinterpret_cast<const float4*>(&red16[(SLOT)^1][8]);  \
      const float4 m3 = *reinterpret_cast<const float4*>(&red16[(SLOT)^1][12]); \
      float mm = fmaxf(fmaxf(fmaxf(m0.x, m0.y), fmaxf(m0.z, m0.w)),          \
                       fmaxf(fmaxf(m1.x, m1.y), fmaxf(m1.z, m1.w)));         \
      mm = fmaxf(mm, fmaxf(fmaxf(fmaxf(m2.x, m2.y), fmaxf(m2.z, m2.w)),     \
                           fmaxf(fmaxf(m3.x, m3.y), fmaxf(m3.z, m3.w))));   \
      D = flog2(mm);                                                         \
      Cc += D;                                                               \
    }                                                                        \
    const float* pp = p_sh[BUF];                                             \
    v2f sA0 = {0.f,0.f}, sA1 = {0.f,0.f}, sA2 = {0.f,0.f}, sA3 = {0.f,0.f};  \
    v2f sB0 = {0.f,0.f}, sB1 = {0.f,0.f}, sB2 = {0.f,0.f}, sB3 = {0.f,0.f};  \
    _Pragma("unroll")                                                        \
    for (int c = 0; c < 4; ++c) {                                            \
      const int w0 = r0 + 4 * (c ^ cs);                                      \
      const float4 pv = *reinterpret_cast<const float4*>(pp + w0);           \
      const v2f pA = {pv.x, pv.y};                                           \
      const v2f pB = {pv.z, pv.w};                                           \
      sA0 = __builtin_elementwise_fma(pA, E[0][2 * c + 0], sA0);             \
      sB0 = __builtin_elementwise_fma(pB, E[0][2 * c + 1], sB0);             \
      sA1 = __builtin_elementwise_fma(pA, E[1][2 * c + 0], sA1);             \
      sB1 = __builtin_elementwise_fma(pB, E[1][2 * c + 1], sB1);             \
      sA2 = __builtin_elementwise_fma(pA, E[2][2 * c + 0], sA2);             \
      sB2 = __builtin_elementwise_fma(pB, E[2][2 * c + 1], sB2);             \
      sA3 = __builtin_elementwise_fma(pA, E[3][2 * c + 0], sA3);             \
      sB3 = __builtin_elementwise_fma(pB, E[3][2 * c + 1], sB3);             \
    }                                                                        \
    const v2f t0 = sA0 + sB0, t1 = sA1 + sB1, t2 = sA2 + sB2, t3 = sA3 + sB3;\
    float a0 = t0.x + t0.y, a1 = t1.x + t1.y;                                \
    float a2 = t2.x + t2.y, a3 = t3.x + t3.y;                                \
    a0 += dpp_mov<0xB1>(a0); a1 += dpp_mov<0xB1>(a1);                        \
    a2 += dpp_mov<0xB1>(a2); a3 += dpp_mov<0xB1>(a3);                        \
    a0 += dpp_mov<0x4E>(a0); a1 += dpp_mov<0x4E>(a1);                        \
    a2 += dpp_mov<0x4E>(a2); a3 += dpp_mov<0x4E>(a3);                        \
    a0 += swz<0x101F>(a0); a1 += swz<0x101F>(a1);                            \
    a2 += swz<0x101F>(a2); a3 += swz<0x101F>(a3);                            \
    const float g0 = fexp2(fmaf(fl.x, LOG2E, -D));                           \
    const float g1 = fexp2(fmaf(fl.y, LOG2E, -D));                           \
    const float g2 = fexp2(fmaf(fl.z, LOG2E, -D));                           \
    const float g3 = fexp2(fmaf(fl.w, LOG2E, -D));                           \
    pc0 = a0 * g0; pc1 = a1 * g1; pc2 = a2 * g2; pc3 = a3 * g3;              \
    if (q == 0) { /* per-instr banks distinct (bank = jg) */                 \
      float* pw = &p_sh[(BUF) ^ 1][jg];                                      \
      pw[0] = pc0; pw[32] = pc1; pw[64] = pc2; pw[96] = pc3;                 \
    }                                                                        \
    if (EVEN) { /* publish 16-lane-row max to slot SLOT */                   \
      float mx = fmaxf(fmaxf(pc0, pc1), fmaxf(pc2, pc3));                    \
      mx = fmaxf(mx, swz<0x201F>(mx));                                       \
      if ((tid & 15) == 0) red16[SLOT][tid >> 4] = mx;                       \
    }                                                                        \
  }

  int t = 0;
  for (; t + 4 <= len; t += 4) {
    BODY(0, FA, 1, 0, t)
    BODY(1, FB, 0, 0, t + 1)
    BODY(0, FC, 1, 1, t + 2)
    BODY(1, FD, 0, 1, t + 3)
  }
  const int rem = len - t;  // block-uniform
  if (rem > 0) BODY(0, FA, 1, 0, t)
  if (rem > 1) BODY(1, FB, 0, 0, t + 1)
  if (rem > 2) BODY(0, FC, 1, 1, t + 2)
#undef BODY

  __syncthreads();  // full drain; separates loop LDS from final reduce

  // alpha2 = log2(p) + Cc; add END transition; block logsumexp (base 2).
  // pc values duplicated across the 8 q-lanes; q==0 contributes sums.
  const float fin0 = flog2(pc0) + Cc + trans[(jg +  0) * K_TAGS + END_TAG] * LOG2E;
  const float fin1 = flog2(pc1) + Cc + trans[(jg + 32) * K_TAGS + END_TAG] * LOG2E;
  const float fin2 = flog2(pc2) + Cc + trans[(jg + 64) * K_TAGS + END_TAG] * LOG2E;
  const float fin3 = flog2(pc3) + Cc + trans[(jg + 96) * K_TAGS + END_TAG] * LOG2E;

  float m = fmaxf(fmaxf(fin0, fin1), fmaxf(fin2, fin3));
#pragma unroll
  for (int off = 8; off < 64; off <<= 1)
    m = fmaxf(m, __shfl_xor(m, off, 64));
  if ((tid & 63) == 0) red8[tid >> 6] = m;
  __syncthreads();
  const float Mf = fmaxf(fmaxf(red8[0], red8[1]), fmaxf(red8[2], red8[3]));

  float e = 0.0f;
  if (q == 0)
    e = (fexp2(fin0 - Mf) + fexp2(fin1 - Mf)) +
        (fexp2(fin2 - Mf) + fexp2(fin3 - Mf));
#pragma unroll
  for (int off = 1; off < 64; off <<= 1)
    e += __shfl_xor(e, off, 64);
  if ((tid & 63) == 0) red8[4 + (tid >> 6)] = e;
  __syncthreads();
  if (tid == 0) {
    const float s = (red8[4] + red8[5]) + (red8[6] + red8[7]);
    partial[b] = (Mf + flog2(s)) * LN2;  // back to natural log
  }
}

// Deterministic reduction of the 512 per-sequence results.
__global__ void crf_reduce(const float* __restrict__ partial,
                           float* __restrict__ out) {
  const int tid = (int)threadIdx.x;  // 256 threads
  float s = partial[tid] + partial[tid + 256];
#pragma unroll
  for (int off = 1; off < 64; off <<= 1) s += __shfl_xor(s, off, 64);
  __shared__ float ws[4];
  if ((tid & 63) == 0) ws[tid >> 6] = s;
  __syncthreads();
  if (tid == 0) out[0] = (ws[0] + ws[1]) + (ws[2] + ws[3]);
}

extern "C" void kernel_launch(void* const* d_in, const int* in_sizes, int n_in,
                              void* d_out, int out_size, void* d_ws, size_t ws_size,
                              hipStream_t stream) {
  const float* feats   = (const float*)d_in[0];
  const float* trans   = (const float*)d_in[1];
  const int*   lengths = (const int*)d_in[2];
  float* partial = (float*)d_ws;   // 512 floats of scratch
  float* out     = (float*)d_out;  // single f32

  crf_fwd_kernel<<<dim3(N_SEQ), dim3(256), 0, stream>>>(feats, trans, lengths, partial);
  crf_reduce<<<dim3(1), dim3(256), 0, stream>>>(partial, out);
}